// Round 1
// baseline (3091.851 us; speedup 1.0000x reference)
//
#include <hip/hip_runtime.h>
#include <math.h>

#define S_LEN 2048
#define DHEAD 64
#define TQ 16
#define KT 256
#define NTILE 8      // S_LEN / KT
#define JREG 32      // S_LEN / 64 score regs per row per lane
#define NBINS 1024
#define LCAP 640     // compacted kept-list capacity per wave

__global__ __launch_bounds__(256, 2)
void dpsa_kernel(const float* __restrict__ Q, const float* __restrict__ K,
                 const float* __restrict__ V, const int* __restrict__ nkp,
                 float* __restrict__ Out) {
  // LDS: QK phase: kbuf 64KB (swizzled K tile).
  // Phase 2 (aliased, per-wave private): hist[4][1024] u32 @0, klist[4][LCAP] @16384,
  // plist[4][LCAP] @16384+4*LCAP*4.  Total 65536 B.
  __shared__ __align__(16) char smem[65536];
  float4*   kbuf4  = (float4*)smem;
  unsigned* hist   = (unsigned*)smem;
  unsigned* klistA = (unsigned*)(smem + 16384);
  float*    plistA = (float*)(smem + 16384 + 4 * LCAP * 4);

  const int tid  = (int)threadIdx.x;
  const int lane = tid & 63;
  const int wid  = tid >> 6;
  const int bid  = (int)blockIdx.x;
  const int bh   = bid >> 7;          // 128 q-blocks per (b,h)
  const int qblk = bid & 127;
  const size_t base = (size_t)bh * (size_t)(S_LEN * DHEAD);
  const float* Kbh = K + base;
  const float* Vbh = V + base;
  const int row0 = qblk * TQ + wid * 4;   // this wave's first query row

  int nk = nkp[0];
  if (nk > S_LEN) nk = S_LEN;

  float s[4][JREG];
  #pragma unroll
  for (int r = 0; r < 4; ++r)
    #pragma unroll
    for (int j = 0; j < JREG; ++j) s[r][j] = 0.f;

  // wave's Q rows, read as wave-uniform global loads (L1 broadcast)
  const float4* Qw = (const float4*)(Q + base + (size_t)row0 * DHEAD);

  // ---------------- QK phase ----------------
  #pragma unroll
  for (int t = 0; t < NTILE; ++t) {
    const float4* Kg = (const float4*)(Kbh + (size_t)t * (KT * DHEAD));
    #pragma unroll
    for (int c = 0; c < 16; ++c) {
      int f   = c * 256 + tid;        // float4 index within 64KB tile
      int key = f >> 4, d4 = f & 15;
      kbuf4[(key << 4) | (d4 ^ (key & 7))] = Kg[f];   // swizzled store
    }
    __syncthreads();
    for (int d4 = 0; d4 < 16; ++d4) {
      float4 q4[4];
      #pragma unroll
      for (int r = 0; r < 4; ++r) q4[r] = Qw[r * 16 + d4];
      #pragma unroll
      for (int i = 0; i < 4; ++i) {
        int key = i * 64 + lane;
        float4 k4 = kbuf4[(key << 4) | (d4 ^ (key & 7))];
        #pragma unroll
        for (int r = 0; r < 4; ++r) {
          float a = s[r][t * 4 + i];
          a = fmaf(q4[r].x, k4.x, a);
          a = fmaf(q4[r].y, k4.y, a);
          a = fmaf(q4[r].z, k4.z, a);
          a = fmaf(q4[r].w, k4.w, a);
          s[r][t * 4 + i] = a;
        }
      }
    }
    __syncthreads();   // last one also fences kbuf before phase-2 aliasing
  }

  #pragma unroll
  for (int r = 0; r < 4; ++r)
    #pragma unroll
    for (int j = 0; j < JREG; ++j) s[r][j] *= 0.125f;   // 1/sqrt(64)

  // ---------------- selection + softmax + PV (per-wave private) ----------------
  unsigned* hw = hist   + wid * NBINS;
  unsigned* kl = klistA + wid * LCAP;
  float*    pl = plistA + wid * LCAP;

  #pragma unroll
  for (int r = 0; r < 4; ++r) {
    // wave-wide max/min of this row's scores
    float vmax = -INFINITY, vmin = INFINITY;
    #pragma unroll
    for (int j = 0; j < JREG; ++j) { vmax = fmaxf(vmax, s[r][j]); vmin = fminf(vmin, s[r][j]); }
    #pragma unroll
    for (int off = 32; off >= 1; off >>= 1) {
      vmax = fmaxf(vmax, __shfl_xor(vmax, off));
      vmin = fminf(vmin, __shfl_xor(vmin, off));
    }

    float thresh = -INFINITY;
    if (nk > 0) {
      float range = vmax - vmin;
      float scale = (range > 0.f) ? ((float)NBINS / range) : 0.f;

      // zero + build per-wave histogram (uniform value bins, exact candidate narrowing)
      #pragma unroll
      for (int b = 0; b < NBINS / 64; ++b) hw[lane + b * 64] = 0u;
      #pragma unroll
      for (int j = 0; j < JREG; ++j) {
        int bb = (int)((s[r][j] - vmin) * scale);
        bb = bb < 0 ? 0 : (bb > NBINS - 1 ? NBINS - 1 : bb);
        atomicAdd(&hw[bb], 1u);
      }

      // suffix scan from the top to find the bin where count-from-top crosses nk
      unsigned A = 0;
      unsigned hv[16];
      #pragma unroll
      for (int i2 = 0; i2 < 16; ++i2) { hv[i2] = hw[lane * 16 + i2]; A += hv[i2]; }
      unsigned ssum = A;
      #pragma unroll
      for (int off = 1; off <= 32; off <<= 1) {
        unsigned u = __shfl_down(ssum, off);
        if (lane + off < 64) ssum += u;
      }
      unsigned cum = ssum - A;          // strictly above this lane's top bin
      int bsel = -1; int mloc = 0;
      #pragma unroll
      for (int i2 = 15; i2 >= 0; --i2) {
        unsigned c0 = cum; cum += hv[i2];
        if (bsel < 0 && c0 < (unsigned)nk && cum >= (unsigned)nk) {
          bsel = lane * 16 + i2; mloc = nk - (int)c0;
        }
      }
      unsigned long long fmask = __ballot(bsel >= 0);
      int srcl = __ffsll(fmask) - 1;
      bsel = __shfl(bsel, srcl);
      int m = __shfl(mloc, srcl);

      // exact m-th largest within the selected bin (duplicate-safe repeated extract)
      unsigned inbin = 0;
      #pragma unroll
      for (int j = 0; j < JREG; ++j) {
        int bb = (int)((s[r][j] - vmin) * scale);
        bb = bb < 0 ? 0 : (bb > NBINS - 1 ? NBINS - 1 : bb);
        if (bb == bsel) inbin |= (1u << j);
      }
      while (true) {
        float cmax = -INFINITY;
        #pragma unroll
        for (int j = 0; j < JREG; ++j) if (inbin & (1u << j)) cmax = fmaxf(cmax, s[r][j]);
        #pragma unroll
        for (int off = 32; off >= 1; off >>= 1) cmax = fmaxf(cmax, __shfl_xor(cmax, off));
        int cnt = 0;
        #pragma unroll
        for (int j = 0; j < JREG; ++j) if ((inbin & (1u << j)) && s[r][j] == cmax) cnt++;
        #pragma unroll
        for (int off = 32; off >= 1; off >>= 1) cnt += __shfl_xor(cnt, off);
        if (m <= cnt) { thresh = cmax; break; }
        m -= cnt;
        #pragma unroll
        for (int j = 0; j < JREG; ++j) if ((inbin & (1u << j)) && s[r][j] == cmax) inbin &= ~(1u << j);
      }
    }

    // softmax (masked entries exactly 0, like exp(-1e18 - max))
    float psum = 0.f;
    #pragma unroll
    for (int j = 0; j < JREG; ++j) {
      float p = (s[r][j] >= thresh) ? expf(s[r][j] - vmax) : 0.f;
      s[r][j] = p;
      psum += p;
    }
    #pragma unroll
    for (int off = 32; off >= 1; off >>= 1) psum += __shfl_xor(psum, off);

    // ballot-compact kept (key, p) pairs into per-wave LDS list
    unsigned nkept = 0;
    #pragma unroll
    for (int j = 0; j < JREG; ++j) {
      bool keep = s[r][j] > 0.f;
      unsigned long long mk = __ballot(keep);
      if (keep) {
        unsigned idx = nkept + (unsigned)__popcll(mk & ((1ull << lane) - 1ull));
        if (idx < LCAP) { kl[idx] = (unsigned)(j * 64 + lane); pl[idx] = s[r][j]; }
      }
      nkept += (unsigned)__popcll(mk);
    }

    // PV gather: dim = lane, coalesced 256B V-row loads
    float acc = 0.f;
    if (nkept <= LCAP) {
      for (unsigned i = 0; i < nkept; ++i) {
        float pp = pl[i];
        int key  = (int)kl[i];
        acc = fmaf(pp, Vbh[(size_t)key * DHEAD + lane], acc);
      }
    } else {
      // robust fallback (only if nk is huge): broadcast p via shfl, walk all keys
      #pragma unroll
      for (int j = 0; j < JREG; ++j) {
        for (int sl = 0; sl < 64; ++sl) {
          float pp = __shfl(s[r][j], sl);
          if (pp > 0.f) acc = fmaf(pp, Vbh[(size_t)(j * 64 + sl) * DHEAD + lane], acc);
        }
      }
    }
    Out[base + (size_t)(row0 + r) * DHEAD + lane] = acc / psum;
  }
}

extern "C" void kernel_launch(void* const* d_in, const int* in_sizes, int n_in,
                              void* d_out, int out_size, void* d_ws, size_t ws_size,
                              hipStream_t stream) {
  const float* q  = (const float*)d_in[0];
  const float* k  = (const float*)d_in[1];
  const float* v  = (const float*)d_in[2];
  const int*   nk = (const int*)d_in[3];
  float* out = (float*)d_out;
  dim3 grid(4 * 16 * (S_LEN / TQ));   // 8192 blocks
  dpsa_kernel<<<grid, 256, 0, stream>>>(q, k, v, nk, out);
}

// Round 3
// 1896.275 us; speedup vs baseline: 1.6305x; 1.6305x over previous
//
#include <hip/hip_runtime.h>
#include <math.h>

#define S_LEN 2048
#define DHEAD 64
#define TQ 16
#define KT 128
#define NTILES (S_LEN / KT)   // 16
#define NBINS 512
#define BPL (NBINS / 64)      // 8 bins per lane
#define LCAP 256
#define THREADS 512

// LDS map (bytes), total 163840 = 160 KiB:
//  [0,131072)        S scores  float[TQ][S_LEN]
//  [131072,147456)   K hi: KT rows x 128B fp16, XOR-swizzled 16B slots
//  [147456,163840)   K lo: same layout
//  after QK (alias): hist u32[8][512] @131072 (16KB)
//                    klist u32[8][256] @147456 (8KB)
//                    plist f32[8][256] @155648 (8KB)
#define SOFF   0
#define KHI    131072
#define KLO    147456
#define HOFF   131072
#define KLOFF  147456
#define PLOFF  155648

typedef _Float16 f16x8 __attribute__((ext_vector_type(8)));
typedef float    f32x4 __attribute__((ext_vector_type(4)));

__global__ __launch_bounds__(THREADS, 2)
void dpsa_kernel(const float* __restrict__ Q, const float* __restrict__ K,
                 const float* __restrict__ V, const int* __restrict__ nkp,
                 float* __restrict__ Out) {
  __shared__ __align__(16) char smem[163840];
  float* Sf = (float*)(smem + SOFF);

  const int tid  = (int)threadIdx.x;
  const int lane = tid & 63;
  const int wid  = tid >> 6;            // 0..7
  const int bid  = (int)blockIdx.x;
  const int bh   = bid >> 7;            // 128 q-blocks per (b,h)
  const int qblk = bid & 127;
  const size_t base = (size_t)bh * (size_t)(S_LEN * DHEAD);
  const float* Kbh = K + base;
  const float* Vbh = V + base;

  int nk = nkp[0];
  if (nk > S_LEN) nk = S_LEN;

  const int g = lane >> 4;        // 0..3 (k-group within MFMA)
  const int m = lane & 15;        // A row / B key-within-16

  // ---------------- A fragments (Q) direct from global, hi/lo split ----------------
  f16x8 a_hi0, a_lo0, a_hi1, a_lo1;
  {
    const float* Qrow = Q + base + (size_t)(qblk * TQ + m) * DHEAD;
    float4 qa = *(const float4*)(Qrow + g * 8);
    float4 qb = *(const float4*)(Qrow + g * 8 + 4);
    float4 qc = *(const float4*)(Qrow + 32 + g * 8);
    float4 qd = *(const float4*)(Qrow + 32 + g * 8 + 4);
    float x[16] = {qa.x,qa.y,qa.z,qa.w, qb.x,qb.y,qb.z,qb.w,
                   qc.x,qc.y,qc.z,qc.w, qd.x,qd.y,qd.z,qd.w};
    #pragma unroll
    for (int j = 0; j < 8; ++j) {
      _Float16 h0 = (_Float16)x[j];
      a_hi0[j] = h0;  a_lo0[j] = (_Float16)(x[j] - (float)h0);
      _Float16 h1 = (_Float16)x[8 + j];
      a_hi1[j] = h1;  a_lo1[j] = (_Float16)(x[8 + j] - (float)h1);
    }
  }

  // ---------------- QK via hi/lo MFMA, S -> LDS ----------------
  const f16x8* Kh = (const f16x8*)(smem + KHI);
  const f16x8* Kl = (const f16x8*)(smem + KLO);
  const int keyl = tid >> 2;      // staging: key 0..127
  const int q4i  = tid & 3;       // staging: 16-d chunk
  const int sw   = keyl & 7;

  float4 pf0, pf1, pf2, pf3;      // register prefetch of K tile
  {
    const float4* Kg4 = (const float4*)Kbh;
    int idx = keyl * 16 + q4i * 4;
    pf0 = Kg4[idx]; pf1 = Kg4[idx + 1]; pf2 = Kg4[idx + 2]; pf3 = Kg4[idx + 3];
  }

  for (int t = 0; t < NTILES; ++t) {
    // convert prefetched tile to hi/lo fp16, write swizzled LDS
    {
      float x[16] = {pf0.x,pf0.y,pf0.z,pf0.w, pf1.x,pf1.y,pf1.z,pf1.w,
                     pf2.x,pf2.y,pf2.z,pf2.w, pf3.x,pf3.y,pf3.z,pf3.w};
      f16x8 hi0, hi1, lo0, lo1;
      #pragma unroll
      for (int j = 0; j < 8; ++j) {
        _Float16 h0 = (_Float16)x[j];
        hi0[j] = h0;  lo0[j] = (_Float16)(x[j] - (float)h0);
        _Float16 h1 = (_Float16)x[8 + j];
        hi1[j] = h1;  lo1[j] = (_Float16)(x[8 + j] - (float)h1);
      }
      f16x8* Khw = (f16x8*)(smem + KHI);
      f16x8* Klw = (f16x8*)(smem + KLO);
      Khw[keyl * 8 + ((q4i * 2)     ^ sw)] = hi0;
      Khw[keyl * 8 + ((q4i * 2 + 1) ^ sw)] = hi1;
      Klw[keyl * 8 + ((q4i * 2)     ^ sw)] = lo0;
      Klw[keyl * 8 + ((q4i * 2 + 1) ^ sw)] = lo1;
    }
    if (t + 1 < NTILES) {   // prefetch next tile (overlaps MFMA phase)
      const float4* Kg4 = (const float4*)(Kbh + (size_t)(t + 1) * (KT * DHEAD));
      int idx = keyl * 16 + q4i * 4;
      pf0 = Kg4[idx]; pf1 = Kg4[idx + 1]; pf2 = Kg4[idx + 2]; pf3 = Kg4[idx + 3];
    }
    __syncthreads();
    {
      int keyr = wid * 16 + m;     // key within tile; keyr&7 == m&7
      int s0 = ( g      ^ (m & 7));
      int s1 = ((4 + g) ^ (m & 7));
      f16x8 b_hi0 = Kh[keyr * 8 + s0];
      f16x8 b_hi1 = Kh[keyr * 8 + s1];
      f16x8 b_lo0 = Kl[keyr * 8 + s0];
      f16x8 b_lo1 = Kl[keyr * 8 + s1];
      f32x4 acc = {0.f, 0.f, 0.f, 0.f};
      acc = __builtin_amdgcn_mfma_f32_16x16x32_f16(a_hi0, b_hi0, acc, 0, 0, 0);
      acc = __builtin_amdgcn_mfma_f32_16x16x32_f16(a_hi1, b_hi1, acc, 0, 0, 0);
      acc = __builtin_amdgcn_mfma_f32_16x16x32_f16(a_hi0, b_lo0, acc, 0, 0, 0);
      acc = __builtin_amdgcn_mfma_f32_16x16x32_f16(a_hi1, b_lo1, acc, 0, 0, 0);
      acc = __builtin_amdgcn_mfma_f32_16x16x32_f16(a_lo0, b_hi0, acc, 0, 0, 0);
      acc = __builtin_amdgcn_mfma_f32_16x16x32_f16(a_lo1, b_hi1, acc, 0, 0, 0);
      int keyabs = t * KT + wid * 16 + m;
      #pragma unroll
      for (int rg = 0; rg < 4; ++rg)
        Sf[(size_t)(g * 4 + rg) * S_LEN + keyabs] = acc[rg] * 0.125f;
    }
    __syncthreads();   // protects K buffers; final one publishes S + frees alias region
  }

  // ---------------- selection + softmax + PV (per-wave, 2 rows each) ----------------
  unsigned* hw = (unsigned*)(smem + HOFF)  + wid * NBINS;
  unsigned* kl = (unsigned*)(smem + KLOFF) + wid * LCAP;
  float*    pl = (float*)(smem + PLOFF)    + wid * LCAP;
  const float4* S4 = (const float4*)(smem + SOFF);

  for (int rr = 0; rr < 2; ++rr) {
    const int row = wid * 2 + rr;
    float4 sv[8];
    #pragma unroll
    for (int j = 0; j < 8; ++j) sv[j] = S4[row * (S_LEN / 4) + j * 64 + lane];
    // value sv[j][c] has key = j*256 + lane*4 + c

    float vmax = -INFINITY, vmin = INFINITY;
    #pragma unroll
    for (int j = 0; j < 8; ++j) {
      vmax = fmaxf(vmax, fmaxf(fmaxf(sv[j].x, sv[j].y), fmaxf(sv[j].z, sv[j].w)));
      vmin = fminf(vmin, fminf(fminf(sv[j].x, sv[j].y), fminf(sv[j].z, sv[j].w)));
    }
    #pragma unroll
    for (int off = 32; off >= 1; off >>= 1) {
      vmax = fmaxf(vmax, __shfl_xor(vmax, off));
      vmin = fminf(vmin, __shfl_xor(vmin, off));
    }

    float sarr[32];
    #pragma unroll
    for (int j = 0; j < 8; ++j) {
      sarr[j*4+0] = sv[j].x; sarr[j*4+1] = sv[j].y;
      sarr[j*4+2] = sv[j].z; sarr[j*4+3] = sv[j].w;
    }

    float thresh = -INFINITY;
    if (nk > 0) {
      float range = vmax - vmin;
      float scale = (range > 0.f) ? ((float)NBINS / range) : 0.f;

      #pragma unroll
      for (int i2 = 0; i2 < BPL; ++i2) hw[(i2 << 6) | lane] = 0u;
      #pragma unroll
      for (int q = 0; q < 32; ++q) {
        int bb = (int)((sarr[q] - vmin) * scale);
        bb = bb < 0 ? 0 : (bb > NBINS - 1 ? NBINS - 1 : bb);
        atomicAdd(&hw[((bb & 7) << 6) | (bb >> 3)], 1u);   // transposed store
      }

      unsigned A = 0; unsigned hv[BPL];
      #pragma unroll
      for (int i2 = 0; i2 < BPL; ++i2) { hv[i2] = hw[(i2 << 6) | lane]; A += hv[i2]; }
      unsigned ssum = A;
      #pragma unroll
      for (int off = 1; off <= 32; off <<= 1) {
        unsigned u = (unsigned)__shfl_down((int)ssum, off);
        if (lane + off < 64) ssum += u;
      }
      unsigned cum = ssum - A;   // count in bins strictly above this lane's top bin
      int bsel = -1; int mloc = 0;
      #pragma unroll
      for (int i2 = BPL - 1; i2 >= 0; --i2) {
        unsigned c0 = cum; cum += hv[i2];
        if (bsel < 0 && c0 < (unsigned)nk && cum >= (unsigned)nk) {
          bsel = (lane << 3) | i2; mloc = nk - (int)c0;
        }
      }
      unsigned long long fm = __ballot(bsel >= 0);
      int srcl = __ffsll(fm) - 1;
      bsel = __shfl(bsel, srcl);
      int mth = __shfl(mloc, srcl);

      unsigned inbin = 0;
      #pragma unroll
      for (int q = 0; q < 32; ++q) {
        int bb = (int)((sarr[q] - vmin) * scale);
        bb = bb < 0 ? 0 : (bb > NBINS - 1 ? NBINS - 1 : bb);
        if (bb == bsel) inbin |= (1u << q);
      }
      while (true) {
        float cmax = -INFINITY;
        #pragma unroll
        for (int q = 0; q < 32; ++q) if (inbin & (1u << q)) cmax = fmaxf(cmax, sarr[q]);
        #pragma unroll
        for (int off = 32; off >= 1; off >>= 1) cmax = fmaxf(cmax, __shfl_xor(cmax, off));
        int cnt = 0;
        #pragma unroll
        for (int q = 0; q < 32; ++q) if ((inbin & (1u << q)) && sarr[q] == cmax) cnt++;
        #pragma unroll
        for (int off = 32; off >= 1; off >>= 1) cnt += __shfl_xor(cnt, off);
        if (mth <= cnt) { thresh = cmax; break; }
        mth -= cnt;
        #pragma unroll
        for (int q = 0; q < 32; ++q) if ((inbin & (1u << q)) && sarr[q] == cmax) inbin &= ~(1u << q);
      }
    }

    // softmax + ballot-compaction
    float pv[32];
    float psum = 0.f;
    #pragma unroll
    for (int q = 0; q < 32; ++q) {
      float p = (sarr[q] >= thresh) ? expf(sarr[q] - vmax) : 0.f;
      pv[q] = p; psum += p;
    }
    #pragma unroll
    for (int off = 32; off >= 1; off >>= 1) psum += __shfl_xor(psum, off);

    unsigned nkept = 0;
    #pragma unroll
    for (int q = 0; q < 32; ++q) {
      bool keep = pv[q] > 0.f;
      unsigned long long mk = __ballot(keep);
      if (keep) {
        unsigned idx = nkept + (unsigned)__popcll(mk & ((1ull << lane) - 1ull));
        if (idx < LCAP) {
          kl[idx] = (unsigned)((q >> 2) * 256 + lane * 4 + (q & 3));
          pl[idx] = pv[q];
        }
      }
      nkept += (unsigned)__popcll(mk);
    }

    float acc0 = 0.f, acc1 = 0.f, acc2 = 0.f, acc3 = 0.f;
    if (nkept <= LCAP) {
      unsigned i = 0;
      for (; i + 4 <= nkept; i += 4) {
        acc0 = fmaf(pl[i+0], Vbh[(size_t)kl[i+0] * DHEAD + lane], acc0);
        acc1 = fmaf(pl[i+1], Vbh[(size_t)kl[i+1] * DHEAD + lane], acc1);
        acc2 = fmaf(pl[i+2], Vbh[(size_t)kl[i+2] * DHEAD + lane], acc2);
        acc3 = fmaf(pl[i+3], Vbh[(size_t)kl[i+3] * DHEAD + lane], acc3);
      }
      for (; i < nkept; ++i)
        acc0 = fmaf(pl[i], Vbh[(size_t)kl[i] * DHEAD + lane], acc0);
    } else {
      // robust fallback (tie overflow): broadcast p via shfl, walk all keys
      #pragma unroll
      for (int q = 0; q < 32; ++q) {
        for (int sl = 0; sl < 64; ++sl) {
          float pp = __shfl(pv[q], sl);
          if (pp > 0.f)
            acc0 = fmaf(pp, Vbh[(size_t)((q >> 2) * 256 + sl * 4 + (q & 3)) * DHEAD + lane], acc0);
        }
      }
    }
    float accv = (acc0 + acc1) + (acc2 + acc3);
    Out[base + (size_t)(qblk * TQ + row) * DHEAD + lane] = accv / psum;
  }
}

extern "C" void kernel_launch(void* const* d_in, const int* in_sizes, int n_in,
                              void* d_out, int out_size, void* d_ws, size_t ws_size,
                              hipStream_t stream) {
  const float* q  = (const float*)d_in[0];
  const float* k  = (const float*)d_in[1];
  const float* v  = (const float*)d_in[2];
  const int*   nk = (const int*)d_in[3];
  float* out = (float*)d_out;
  dim3 grid(4 * 16 * (S_LEN / TQ));   // 8192 blocks
  dpsa_kernel<<<grid, THREADS, 0, stream>>>(q, k, v, nk, out);
}